// Round 6
// baseline (429.420 us; speedup 1.0000x reference)
//
#include <hip/hip_runtime.h>
#include <hip/hip_bf16.h>
#include <stdint.h>

typedef __bf16 bf16;
typedef bf16 bf16x8 __attribute__((ext_vector_type(8)));
typedef float f32x4 __attribute__((ext_vector_type(4)));
typedef uint32_t u32x4 __attribute__((ext_vector_type(4)));

#define MFMA(a, b, c) __builtin_amdgcn_mfma_f32_16x16x32_bf16((a), (b), (c), 0, 0, 0)

__device__ __forceinline__ uint32_t cvt_pk_bf16(float lo, float hi) {
  uint32_t r;
  asm("v_cvt_pk_bf16_f32 %0, %1, %2" : "=v"(r) : "v"(lo), "v"(hi));
  return r;
}

// m(k): physical D-row delivered at B k-slot k by the standard b2-pack
// (verified rounds 1-5: inverse of O1T's sigma).
__device__ __forceinline__ int mk(int k) {
  return 32*(k>>5) + 16*((k>>2)&1) + 4*((k>>3)&3) + (k&3);
}

// ---------------------------------------------------------------------------
// Workspace layout (bytes):
//   fbf    @ 0        : [65536][64] bf16 (f padded, slot57=1.0)    8,388,608
//   O1T    @ 8388608  : [54][128][64] bf16 (perm rows, bias@k57)     884,736
//   O2T    @ 9273344  : [54][3][128] bf16  (pre-scaled by log2e)      41,472
//   blobG  @ 9314816  : mlp LDS blob, 71680 bf16 pre-swizzled        143,360
//   bias64 @ 9458176  : [64] f32  (Nb2|Cb2|1|0)                          256
//   Fb2pad @ 9458432  : [64] f32                                         256
//   xhi    @ 9458688  : [65536][64] bf16 (x pre-permuted, hi)       8,388,608
//   xlo    @ 17847296 : [65536][64] bf16 (lo residual)              8,388,608
//   tmp    @ 26235904 : [54][65536][3] f32 (optional)              42,467,328
// ---------------------------------------------------------------------------

__global__ __launch_bounds__(256) void prep_kernel(
    const float* __restrict__ x,
    const float* __restrict__ Cw1, const float* __restrict__ Cb1,
    const float* __restrict__ Cw2, const float* __restrict__ Cb2,
    const float* __restrict__ Nw1, const float* __restrict__ Nb1,
    const float* __restrict__ Nw2, const float* __restrict__ Nb2,
    const float* __restrict__ Fw1, const float* __restrict__ Fb1,
    const float* __restrict__ Fw2, const float* __restrict__ Fb2,
    const float* __restrict__ Ow1, const float* __restrict__ Ob1,
    const float* __restrict__ Ow2,
    bf16* __restrict__ O1T, bf16* __restrict__ O2T,
    bf16* __restrict__ blobG, float* __restrict__ bias64,
    float* __restrict__ Fb2pad, bf16* __restrict__ xhi, bf16* __restrict__ xlo)
{
  const float LOG2E = 1.4426950408889634f;
  int gid = blockIdx.x * 256 + threadIdx.x;
  // O1T[br][m][k] = Ow1[br][k][sigma(m)] (k<57), Ob1[br][sigma(m)] (k==57), 0 else
  if (gid < 442368) {
    int m  = gid & 127;
    int k  = (gid >> 7) & 63;
    int br = gid >> 13;
    int c  = ((m >> 5) << 5) | (((m >> 2) & 3) << 3) | (((m >> 4) & 1) << 2) | (m & 3);
    float v = 0.f;
    if (k < 57)       v = Ow1[(br * 57 + k) * 128 + c];
    else if (k == 57) v = Ob1[br * 128 + c];
    O1T[(br * 128 + m) * 64 + k] = (bf16)v;
    return;
  }
  gid -= 442368;
  // O2T[br][e][c] = Ow2[br][c][e] * log2e  (softmax done in base-2 domain)
  if (gid < 20736) {
    int br  = gid / 384;
    int rem = gid - br * 384;
    int e   = rem >> 7;
    int cc  = rem & 127;
    O2T[gid] = (bf16)(Ow2[(br * 128 + cc) * 3 + e] * LOG2E);
    return;
  }
  gid -= 20736;
  if (gid < 71680) {
    int idx = gid;
    float w = 0.f;
    bool lo = false;
    if (idx < 16384) {                       // A1N hi/lo [128 j][64 k]
      lo = idx >= 8192; int l = idx & 8191;
      int j = l >> 6, cp = l & 63;
      int k = (((cp >> 3) ^ (j & 7)) << 3) | (cp & 7);
      if (k < 54) w = Nw1[k * 128 + j];
      else if (k == 54) w = Nb1[j];
    } else if (idx < 20480) {                // A1C hi [128 j][32 kl] (slots 32+kl)
      int l = idx - 16384;
      int j = l >> 5, cp = l & 31;
      int kl = (((cp >> 3) ^ (j & 3)) << 3) | (cp & 7);
      int s = 32 + kl;
      if (s == 54) w = Cb1[j];
      else if (s >= 56 && s <= 59) w = Cw1[(s - 56) * 128 + j];
    } else if (idx < 36864) {                // A2N hi/lo [64 o][128 k]
      int l = idx - 20480; lo = l >= 8192; l &= 8191;
      int o = l >> 7, cp = l & 127;
      int k = (((cp >> 3) ^ (o & 7)) << 3) | (cp & 7);
      int p = mk(k);
      if (o < 54) w = Nw2[p * 54 + o];
    } else if (idx < 38912) {                // A2C16 hi [16 o'][128 k] (rows 48+o')
      int l = idx - 36864;
      int o = l >> 7, cp = l & 127;
      int k = (((cp >> 3) ^ (o & 7)) << 3) | (cp & 7);
      int p = mk(k);
      if (o >= 6 && o <= 8) w = Cw2[p * 3 + (o - 6)];
    } else if (idx < 55296) {                // A1F hi/lo [128 j][64 k]
      int l = idx - 38912; lo = l >= 8192; l &= 8191;
      int j = l >> 6, cp = l & 63;
      int k = (((cp >> 3) ^ (j & 7)) << 3) | (cp & 7);
      int p = mk(k);
      if (p < 54) w = Fw1[(3 + p) * 128 + j];
      else if (p < 57) w = Fw1[(p - 54) * 128 + j];
      else if (p == 57) w = Fb1[j];
    } else {                                 // A2F hi/lo [64 o][128 k]
      int l = idx - 55296; lo = l >= 8192; l &= 8191;
      int o = l >> 7, cp = l & 127;
      int k = (((cp >> 3) ^ (o & 7)) << 3) | (cp & 7);
      int p = mk(k);
      if (o < 57) w = Fw2[p * 57 + o];
    }
    bf16 h = (bf16)w;
    blobG[gid] = lo ? (bf16)(w - (float)h) : h;
    return;
  }
  gid -= 71680;
  if (gid < 64) {
    float v = 0.f;
    if (gid < 54) v = Nb2[gid];
    else if (gid < 57) v = Cb2[gid - 54];
    else if (gid == 57) v = 1.0f;            // constant-1 row -> F bias slot
    bias64[gid] = v;
    return;
  }
  gid -= 64;
  if (gid < 64) { Fb2pad[gid] = (gid < 57) ? Fb2[gid] : 0.f; return; }
  gid -= 64;
  // x pre-permute + hi/lo split: slots 0-53 = x[4+s], 54 = 1.0, 56-59 = x[0..3]
  if (gid < 524288) {
    int row = gid >> 3;
    int s0 = (gid & 7) * 8;
    const float* xr = x + (size_t)row * 58;
    bf16x8 h8, l8;
#pragma unroll
    for (int u = 0; u < 8; ++u) {
      int s = s0 + u;
      float v;
      if (s < 54) v = xr[4 + s];
      else if (s == 54) v = 1.0f;
      else if (s >= 56 && s <= 59) v = xr[s - 56];
      else v = 0.0f;
      bf16 h = (bf16)v;
      h8[u] = h;
      l8[u] = (bf16)(v - (float)h);
    }
    *(bf16x8*)(xhi + (size_t)row * 64 + s0) = h8;
    *(bf16x8*)(xlo + (size_t)row * 64 + s0) = l8;
  }
}

// ---------------------------------------------------------------------------
// mlp kernel: C/N/F via bf16 hi/lo 3-pass MFMA (fp32-grade accuracy).
// Block = 512 thr = 8 waves; grid = 512; ONE 16-row tile per wave.
// B-fragments come pre-permuted/pre-split from xhi/xlo (4 coalesced 16B
// loads) -- removes the 16 scattered scalar x loads + ~50 VALU/lane of
// round 5. ks loops stay unroll-1 to bound ds_read hoisting (spill fix).
// ---------------------------------------------------------------------------
__global__ __launch_bounds__(512)
void mlp_kernel(
    const bf16* __restrict__ xhi, const bf16* __restrict__ xlo,
    const bf16* __restrict__ blobG,
    const float* __restrict__ bias64, const float* __restrict__ Fb2pad,
    bf16* __restrict__ fbf)
{
  __shared__ bf16 blob[71680];
  const int tid = threadIdx.x;
  {
    const uint4* src = (const uint4*)blobG;
    uint4* dst = (uint4*)blob;
    for (int t = tid; t < 8960; t += 512) dst[t] = src[t];
  }
  __syncthreads();

  const int wave = tid >> 6;
  const int lane = tid & 63;
  const int lr = lane & 15;
  const int g = lane >> 4;
  const f32x4 zero4 = {0.f, 0.f, 0.f, 0.f};

  auto frag = [&](int base, int stride, int row_, int chunk, int mask) -> bf16x8 {
    int c = chunk ^ (row_ & mask);
    return *(const bf16x8*)(blob + base + row_ * stride + c * 8);
  };

  const int row = blockIdx.x * 128 + wave * 16 + lr;

  bf16x8 bxh[2], bxl[2];
  bxh[0] = *(const bf16x8*)(xhi + (size_t)row * 64 + g * 8);
  bxh[1] = *(const bf16x8*)(xhi + (size_t)row * 64 + 32 + g * 8);
  bxl[0] = *(const bf16x8*)(xlo + (size_t)row * 64 + g * 8);
  bxl[1] = *(const bf16x8*)(xlo + (size_t)row * 64 + 32 + g * 8);

  // ---- N/C: layer1 tiles produced lazily, consumed by layer2 slice ks ----
  f32x4 acc2[4];
#pragma unroll
  for (int mt = 0; mt < 4; ++mt)
    acc2[mt] = *(const f32x4*)(bias64 + mt * 16 + 4 * g);
#pragma unroll 1
  for (int ks = 0; ks < 4; ++ks) {
    f32x4 aN[2], aC[2];
#pragma unroll
    for (int h = 0; h < 2; ++h) {
      const int mt = 2 * ks + h;
      f32x4 a = zero4;
#pragma unroll
      for (int k2 = 0; k2 < 2; ++k2) {
        bf16x8 aH = frag(0,    64, mt * 16 + lr, k2 * 4 + g, 7);
        bf16x8 aL = frag(8192, 64, mt * 16 + lr, k2 * 4 + g, 7);
        a = MFMA(aH, bxh[k2], a);
        a = MFMA(aH, bxl[k2], a);
        a = MFMA(aL, bxh[k2], a);
      }
      aN[h] = a;
      bf16x8 c8 = frag(16384, 32, mt * 16 + lr, g, 3);
      f32x4 c = MFMA(c8, bxh[1], zero4);
      c = MFMA(c8, bxl[1], c);
      aC[h] = c;
    }
    bf16x8 nh, nl, ch, cl;
#pragma unroll
    for (int u = 0; u < 8; ++u) {
      float vN = fmaxf(aN[u >> 2][u & 3], 0.f);
      bf16 hN = (bf16)vN;
      nh[u] = hN;
      nl[u] = (bf16)(vN - (float)hN);
      float vC = fmaxf(aC[u >> 2][u & 3], 0.f);
      bf16 hC = (bf16)vC;
      ch[u] = hC;
      cl[u] = (bf16)(vC - (float)hC);
    }
#pragma unroll
    for (int mt = 0; mt < 4; ++mt) {
      bf16x8 aH = frag(20480, 128, mt * 16 + lr, ks * 4 + g, 7);
      bf16x8 aL = frag(28672, 128, mt * 16 + lr, ks * 4 + g, 7);
      acc2[mt] = MFMA(aH, nh, acc2[mt]);
      acc2[mt] = MFMA(aH, nl, acc2[mt]);
      acc2[mt] = MFMA(aL, nh, acc2[mt]);
    }
    bf16x8 aCc = frag(36864, 128, lr, ks * 4 + g, 7);
    acc2[3] = MFMA(aCc, ch, acc2[3]);
    acc2[3] = MFMA(aCc, cl, acc2[3]);
  }

  // split (no relu) -> F input frags; acc2 dies here
  bf16x8 b2fh[2], b2fl[2];
#pragma unroll
  for (int s = 0; s < 2; ++s) {
#pragma unroll
    for (int u = 0; u < 8; ++u) {
      float v = acc2[2 * s + (u >> 2)][u & 3];
      bf16 h = (bf16)v;
      b2fh[s][u] = h;
      b2fl[s][u] = (bf16)(v - (float)h);
    }
  }

  // ---- F: layer1 tiles lazy, consumed by F-layer2 slice ks ----
  f32x4 accO[4];
#pragma unroll
  for (int mt = 0; mt < 4; ++mt)
    accO[mt] = *(const f32x4*)(Fb2pad + mt * 16 + 4 * g);
#pragma unroll 1
  for (int ks = 0; ks < 4; ++ks) {
    f32x4 aF[2];
#pragma unroll
    for (int h = 0; h < 2; ++h) {
      const int mt = 2 * ks + h;
      f32x4 a = zero4;
#pragma unroll
      for (int k2 = 0; k2 < 2; ++k2) {
        bf16x8 aH = frag(38912, 64, mt * 16 + lr, k2 * 4 + g, 7);
        bf16x8 aL = frag(47104, 64, mt * 16 + lr, k2 * 4 + g, 7);
        a = MFMA(aH, b2fh[k2], a);
        a = MFMA(aH, b2fl[k2], a);
        a = MFMA(aL, b2fh[k2], a);
      }
      aF[h] = a;
    }
    bf16x8 bh, bl;
#pragma unroll
    for (int u = 0; u < 8; ++u) {
      float v = fmaxf(aF[u >> 2][u & 3], 0.f);
      bf16 h = (bf16)v;
      bh[u] = h;
      bl[u] = (bf16)(v - (float)h);
    }
#pragma unroll
    for (int mt = 0; mt < 4; ++mt) {
      bf16x8 aH = frag(55296, 128, mt * 16 + lr, ks * 4 + g, 7);
      bf16x8 aL = frag(63488, 128, mt * 16 + lr, ks * 4 + g, 7);
      accO[mt] = MFMA(aH, bh, accO[mt]);
      accO[mt] = MFMA(aH, bl, accO[mt]);
      accO[mt] = MFMA(aL, bh, accO[mt]);
    }
  }
  if (g == 2) accO[3][1] = 1.0f;  // f slot 57 = 1.0 (heads bias trick)

  // store f row (bf16, natural slot order)
#pragma unroll
  for (int mt = 0; mt < 4; ++mt) {
    uint32_t w0 = cvt_pk_bf16(accO[mt][0], accO[mt][1]);
    uint32_t w1 = cvt_pk_bf16(accO[mt][2], accO[mt][3]);
    *(uint2*)(fbf + (size_t)row * 64 + mt * 16 + 4 * g) = make_uint2(w0, w1);
  }
}

// ---------------------------------------------------------------------------
// heads: wave = one branch, O1T weights in VGPRs, W2 in LDS (768B), stream
// rows. Grid = 54 branches x 128 chunks (6912 waves = 6.75/SIMD). VGPR
// pinned <=64 by __launch_bounds__(64,8) for 8-wave occupancy headroom.
// Logits are in base-2 domain (W2/bias pre-scaled by log2e) -> exp2 direct.
// ---------------------------------------------------------------------------
template<bool USE_TMP>
__global__ __launch_bounds__(64, 8) void heads_kernel(
    const bf16* __restrict__ fbf, const bf16* __restrict__ O1T,
    const bf16* __restrict__ O2T, const float* __restrict__ Ob2,
    float* __restrict__ tmp, float* __restrict__ out)
{
  __shared__ bf16 w2s[384];
  const int bid = blockIdx.x;
  const int br = bid % 54;
  const int chunk = bid / 54;
  const int lane = threadIdx.x;
  const int lr = lane & 15;
  const int g = lane >> 4;
  const f32x4 zero4 = {0.f, 0.f, 0.f, 0.f};

  if (lane < 48) ((uint4*)w2s)[lane] = ((const uint4*)(O2T + br * 384))[lane];

  // branch L1 weights -> registers (once)
  const bf16* a1p = O1T + br * 8192 + lr * 64 + g * 8;
  bf16x8 a1[8][2];
#pragma unroll
  for (int mt = 0; mt < 8; ++mt)
#pragma unroll
    for (int ks = 0; ks < 2; ++ks)
      a1[mt][ks] = *(const bf16x8*)(a1p + mt * 1024 + ks * 32);

  const float LOG2E = 1.4426950408889634f;
  const float b0 = Ob2[br * 3 + 0] * LOG2E;
  const float b1 = Ob2[br * 3 + 1] * LOG2E;
  const float b2s = Ob2[br * 3 + 2] * LOG2E;

  __syncthreads();
  const int e_clamp = (lr < 2) ? lr : 2;
  const bf16* w2b = w2s + e_clamp * 128 + g * 8;

  const int row0 = chunk * 512 + lr;
  const bf16* fp = fbf + (size_t)row0 * 64 + g * 8;
  float* tp = tmp + ((size_t)br * 65536 + row0) * 3;
  float* op = out + (size_t)row0 * 162 + br * 3;

#pragma unroll 1
  for (int it = 0; it < 32; ++it) {
    bf16x8 fb0 = *(const bf16x8*)(fp);
    bf16x8 fb1 = *(const bf16x8*)(fp + 32);
    fp += 1024;

    f32x4 l2 = zero4;
#pragma unroll
    for (int s2 = 0; s2 < 4; ++s2) {
      f32x4 aA = MFMA(a1[2 * s2][0], fb0, zero4);
      f32x4 aB = MFMA(a1[2 * s2 + 1][0], fb0, zero4);
      aA = MFMA(a1[2 * s2][1], fb1, aA);
      aB = MFMA(a1[2 * s2 + 1][1], fb1, aB);
      u32x4 bw;
      bw[0] = cvt_pk_bf16(fmaxf(aA[0], 0.f), fmaxf(aA[1], 0.f));
      bw[1] = cvt_pk_bf16(fmaxf(aA[2], 0.f), fmaxf(aA[3], 0.f));
      bw[2] = cvt_pk_bf16(fmaxf(aB[0], 0.f), fmaxf(aB[1], 0.f));
      bw[3] = cvt_pk_bf16(fmaxf(aB[2], 0.f), fmaxf(aB[3], 0.f));
      bf16x8 w2v = *(const bf16x8*)(w2b + s2 * 32);
      l2 = MFMA(w2v, __builtin_bit_cast(bf16x8, bw), l2);
    }

    float l0 = l2[0] + b0;
    float l1 = l2[1] + b1;
    float lv = l2[2] + b2s;
    float m = fmaxf(fmaxf(l0, l1), lv);
    float p0 = __builtin_amdgcn_exp2f(l0 - m);
    float p1 = __builtin_amdgcn_exp2f(l1 - m);
    float p2 = __builtin_amdgcn_exp2f(lv - m);
    float rs = __builtin_amdgcn_rcpf(p0 + p1 + p2);
    if (g == 0) {
      if (USE_TMP) {
        tp[0] = p0 * rs; tp[1] = p1 * rs; tp[2] = p2 * rs;
      } else {
        op[0] = p0 * rs; op[1] = p1 * rs; op[2] = p2 * rs;
      }
    }
    if (USE_TMP) tp += 48; else op += 16 * 162;
  }
}

// ---------------------------------------------------------------------------
// transpose: tmp[54][65536][3] -> out[65536][162], coalesced both sides.
// ---------------------------------------------------------------------------
__global__ __launch_bounds__(256) void transpose_kernel(
    const float* __restrict__ tmp, float* __restrict__ out)
{
  __shared__ float sh[64 * 163];
  const int tid = threadIdx.x;
  const int rowbase = blockIdx.x * 64;
  for (int t = tid; t < 10368; t += 256) {
    int p = t / 192;
    int q = t - p * 192;
    int r = q / 3;
    int e = q - r * 3;
    sh[r * 163 + p * 3 + e] = tmp[((size_t)p * 65536 + rowbase + r) * 3 + e];
  }
  __syncthreads();
  for (int t = tid; t < 10368; t += 256) {
    int r = t / 162;
    int c = t - r * 162;
    out[(size_t)(rowbase + r) * 162 + c] = sh[r * 163 + c];
  }
}

// ---------------------------------------------------------------------------
extern "C" void kernel_launch(void* const* d_in, const int* in_sizes, int n_in,
                              void* d_out, int out_size, void* d_ws, size_t ws_size,
                              hipStream_t stream)
{
  (void)in_sizes; (void)n_in; (void)out_size;
  const float* x   = (const float*)d_in[0];
  const float* Cw1 = (const float*)d_in[1];
  const float* Cb1 = (const float*)d_in[2];
  const float* Cw2 = (const float*)d_in[3];
  const float* Cb2 = (const float*)d_in[4];
  const float* Nw1 = (const float*)d_in[5];
  const float* Nb1 = (const float*)d_in[6];
  const float* Nw2 = (const float*)d_in[7];
  const float* Nb2 = (const float*)d_in[8];
  const float* Fw1 = (const float*)d_in[9];
  const float* Fb1 = (const float*)d_in[10];
  const float* Fw2 = (const float*)d_in[11];
  const float* Fb2 = (const float*)d_in[12];
  const float* Ow1 = (const float*)d_in[13];
  const float* Ob1 = (const float*)d_in[14];
  const float* Ow2 = (const float*)d_in[15];
  const float* Ob2 = (const float*)d_in[16];

  char* ws = (char*)d_ws;
  bf16*  fbf    = (bf16*)(ws + 0);
  bf16*  O1T    = (bf16*)(ws + 8388608);
  bf16*  O2T    = (bf16*)(ws + 9273344);
  bf16*  blobG  = (bf16*)(ws + 9314816);
  float* bias64 = (float*)(ws + 9458176);
  float* Fb2pad = (float*)(ws + 9458432);
  bf16*  xhi    = (bf16*)(ws + 9458688);
  bf16*  xlo    = (bf16*)(ws + 17847296);
  float* tmp    = (float*)(ws + 26235904);
  const size_t need = 26235904ull + 42467328ull;
  const bool useTmp = ws_size >= need;

  prep_kernel<<<4138, 256, 0, stream>>>(x, Cw1, Cb1, Cw2, Cb2, Nw1, Nb1, Nw2, Nb2,
                                        Fw1, Fb1, Fw2, Fb2, Ow1, Ob1, Ow2,
                                        O1T, O2T, blobG, bias64, Fb2pad, xhi, xlo);
  mlp_kernel<<<512, 512, 0, stream>>>(xhi, xlo, blobG, bias64, Fb2pad, fbf);
  if (useTmp) {
    heads_kernel<true><<<6912, 64, 0, stream>>>(fbf, O1T, O2T, Ob2, tmp, (float*)d_out);
    transpose_kernel<<<1024, 256, 0, stream>>>(tmp, (float*)d_out);
  } else {
    heads_kernel<false><<<6912, 64, 0, stream>>>(fbf, O1T, O2T, Ob2, tmp, (float*)d_out);
  }
}

// Round 7
// 233.838 us; speedup vs baseline: 1.8364x; 1.8364x over previous
//
#include <hip/hip_runtime.h>
#include <hip/hip_bf16.h>
#include <stdint.h>

typedef __bf16 bf16;
typedef bf16 bf16x8 __attribute__((ext_vector_type(8)));
typedef float f32x4 __attribute__((ext_vector_type(4)));
typedef uint32_t u32x4 __attribute__((ext_vector_type(4)));

#define MFMA(a, b, c) __builtin_amdgcn_mfma_f32_16x16x32_bf16((a), (b), (c), 0, 0, 0)

__device__ __forceinline__ uint32_t cvt_pk_bf16(float lo, float hi) {
  uint32_t r;
  asm("v_cvt_pk_bf16_f32 %0, %1, %2" : "=v"(r) : "v"(lo), "v"(hi));
  return r;
}

// m(k): physical D-row delivered at B k-slot k by the standard b2-pack
// (verified rounds 1-6: inverse of O1T's sigma).
__device__ __forceinline__ int mk(int k) {
  return 32*(k>>5) + 16*((k>>2)&1) + 4*((k>>3)&3) + (k&3);
}

// ---------------------------------------------------------------------------
// Workspace layout (bytes):
//   fbf    @ 0        : [65536][64] bf16 (f padded, slot57=1.0)    8,388,608
//   O1T    @ 8388608  : [54][128][64] bf16 (perm rows, bias@k57)     884,736
//   O2T    @ 9273344  : [54][3][128] bf16  (pre-scaled by log2e)      41,472
//   blobG  @ 9314816  : mlp LDS blob, 71680 bf16 pre-swizzled        143,360
//   bias64 @ 9458176  : [64] f32  (Nb2|Cb2|1|0)                          256
//   Fb2pad @ 9458432  : [64] f32                                         256
//   xhi    @ 9458688  : [65536][64] bf16 (x pre-permuted, hi)       8,388,608
//   xlo    @ 17847296 : [65536][64] bf16 (lo residual)              8,388,608
//   tmp    @ 26235904 : [54][65536][3] f32 (optional)              42,467,328
// ---------------------------------------------------------------------------

__global__ __launch_bounds__(256) void prep_kernel(
    const float* __restrict__ x,
    const float* __restrict__ Cw1, const float* __restrict__ Cb1,
    const float* __restrict__ Cw2, const float* __restrict__ Cb2,
    const float* __restrict__ Nw1, const float* __restrict__ Nb1,
    const float* __restrict__ Nw2, const float* __restrict__ Nb2,
    const float* __restrict__ Fw1, const float* __restrict__ Fb1,
    const float* __restrict__ Fw2, const float* __restrict__ Fb2,
    const float* __restrict__ Ow1, const float* __restrict__ Ob1,
    const float* __restrict__ Ow2,
    bf16* __restrict__ O1T, bf16* __restrict__ O2T,
    bf16* __restrict__ blobG, float* __restrict__ bias64,
    float* __restrict__ Fb2pad, bf16* __restrict__ xhi, bf16* __restrict__ xlo)
{
  const float LOG2E = 1.4426950408889634f;
  int gid = blockIdx.x * 256 + threadIdx.x;
  // O1T[br][m][k] = Ow1[br][k][sigma(m)] (k<57), Ob1[br][sigma(m)] (k==57), 0 else
  if (gid < 442368) {
    int m  = gid & 127;
    int k  = (gid >> 7) & 63;
    int br = gid >> 13;
    int c  = ((m >> 5) << 5) | (((m >> 2) & 3) << 3) | (((m >> 4) & 1) << 2) | (m & 3);
    float v = 0.f;
    if (k < 57)       v = Ow1[(br * 57 + k) * 128 + c];
    else if (k == 57) v = Ob1[br * 128 + c];
    O1T[(br * 128 + m) * 64 + k] = (bf16)v;
    return;
  }
  gid -= 442368;
  // O2T[br][e][c] = Ow2[br][c][e] * log2e  (softmax done in base-2 domain)
  if (gid < 20736) {
    int br  = gid / 384;
    int rem = gid - br * 384;
    int e   = rem >> 7;
    int cc  = rem & 127;
    O2T[gid] = (bf16)(Ow2[(br * 128 + cc) * 3 + e] * LOG2E);
    return;
  }
  gid -= 20736;
  if (gid < 71680) {
    int idx = gid;
    float w = 0.f;
    bool lo = false;
    if (idx < 16384) {                       // A1N hi/lo [128 j][64 k]
      lo = idx >= 8192; int l = idx & 8191;
      int j = l >> 6, cp = l & 63;
      int k = (((cp >> 3) ^ (j & 7)) << 3) | (cp & 7);
      if (k < 54) w = Nw1[k * 128 + j];
      else if (k == 54) w = Nb1[j];
    } else if (idx < 20480) {                // A1C hi [128 j][32 kl] (slots 32+kl)
      int l = idx - 16384;
      int j = l >> 5, cp = l & 31;
      int kl = (((cp >> 3) ^ (j & 3)) << 3) | (cp & 7);
      int s = 32 + kl;
      if (s == 54) w = Cb1[j];
      else if (s >= 56 && s <= 59) w = Cw1[(s - 56) * 128 + j];
    } else if (idx < 36864) {                // A2N hi/lo [64 o][128 k]
      int l = idx - 20480; lo = l >= 8192; l &= 8191;
      int o = l >> 7, cp = l & 127;
      int k = (((cp >> 3) ^ (o & 7)) << 3) | (cp & 7);
      int p = mk(k);
      if (o < 54) w = Nw2[p * 54 + o];
    } else if (idx < 38912) {                // A2C16 hi [16 o'][128 k] (rows 48+o')
      int l = idx - 36864;
      int o = l >> 7, cp = l & 127;
      int k = (((cp >> 3) ^ (o & 7)) << 3) | (cp & 7);
      int p = mk(k);
      if (o >= 6 && o <= 8) w = Cw2[p * 3 + (o - 6)];
    } else if (idx < 55296) {                // A1F hi/lo [128 j][64 k]
      int l = idx - 38912; lo = l >= 8192; l &= 8191;
      int j = l >> 6, cp = l & 63;
      int k = (((cp >> 3) ^ (j & 7)) << 3) | (cp & 7);
      int p = mk(k);
      if (p < 54) w = Fw1[(3 + p) * 128 + j];
      else if (p < 57) w = Fw1[(p - 54) * 128 + j];
      else if (p == 57) w = Fb1[j];
    } else {                                 // A2F hi/lo [64 o][128 k]
      int l = idx - 55296; lo = l >= 8192; l &= 8191;
      int o = l >> 7, cp = l & 127;
      int k = (((cp >> 3) ^ (o & 7)) << 3) | (cp & 7);
      int p = mk(k);
      if (o < 57) w = Fw2[p * 57 + o];
    }
    bf16 h = (bf16)w;
    blobG[gid] = lo ? (bf16)(w - (float)h) : h;
    return;
  }
  gid -= 71680;
  if (gid < 64) {
    float v = 0.f;
    if (gid < 54) v = Nb2[gid];
    else if (gid < 57) v = Cb2[gid - 54];
    else if (gid == 57) v = 1.0f;            // constant-1 row -> F bias slot
    bias64[gid] = v;
    return;
  }
  gid -= 64;
  if (gid < 64) { Fb2pad[gid] = (gid < 57) ? Fb2[gid] : 0.f; return; }
  gid -= 64;
  // x pre-permute + hi/lo split: slots 0-53 = x[4+s], 54 = 1.0, 56-59 = x[0..3]
  if (gid < 524288) {
    int row = gid >> 3;
    int s0 = (gid & 7) * 8;
    const float* xr = x + (size_t)row * 58;
    bf16x8 h8, l8;
#pragma unroll
    for (int u = 0; u < 8; ++u) {
      int s = s0 + u;
      float v;
      if (s < 54) v = xr[4 + s];
      else if (s == 54) v = 1.0f;
      else if (s >= 56 && s <= 59) v = xr[s - 56];
      else v = 0.0f;
      bf16 h = (bf16)v;
      h8[u] = h;
      l8[u] = (bf16)(v - (float)h);
    }
    *(bf16x8*)(xhi + (size_t)row * 64 + s0) = h8;
    *(bf16x8*)(xlo + (size_t)row * 64 + s0) = l8;
  }
}

// ---------------------------------------------------------------------------
// mlp kernel: C/N/F via bf16 hi/lo 3-pass MFMA (fp32-grade accuracy).
// Block = 1024 thr = 16 waves; grid = 256 (1 block/CU, 16 waves/CU = 4/SIMD
// -- was 2/SIMD at block 512); ONE 16-row tile per wave. ks loops unroll-1
// to bound ds_read hoisting (the round-2..4 spill fix).
// ---------------------------------------------------------------------------
__global__ __launch_bounds__(1024)
void mlp_kernel(
    const bf16* __restrict__ xhi, const bf16* __restrict__ xlo,
    const bf16* __restrict__ blobG,
    const float* __restrict__ bias64, const float* __restrict__ Fb2pad,
    bf16* __restrict__ fbf)
{
  __shared__ bf16 blob[71680];
  const int tid = threadIdx.x;
  {
    const uint4* src = (const uint4*)blobG;
    uint4* dst = (uint4*)blob;
    for (int t = tid; t < 8960; t += 1024) dst[t] = src[t];
  }
  __syncthreads();

  const int wave = tid >> 6;
  const int lane = tid & 63;
  const int lr = lane & 15;
  const int g = lane >> 4;
  const f32x4 zero4 = {0.f, 0.f, 0.f, 0.f};

  auto frag = [&](int base, int stride, int row_, int chunk, int mask) -> bf16x8 {
    int c = chunk ^ (row_ & mask);
    return *(const bf16x8*)(blob + base + row_ * stride + c * 8);
  };

  const int row = blockIdx.x * 256 + wave * 16 + lr;

  bf16x8 bxh[2], bxl[2];
  bxh[0] = *(const bf16x8*)(xhi + (size_t)row * 64 + g * 8);
  bxh[1] = *(const bf16x8*)(xhi + (size_t)row * 64 + 32 + g * 8);
  bxl[0] = *(const bf16x8*)(xlo + (size_t)row * 64 + g * 8);
  bxl[1] = *(const bf16x8*)(xlo + (size_t)row * 64 + 32 + g * 8);

  // ---- N/C: layer1 tiles produced lazily, consumed by layer2 slice ks ----
  f32x4 acc2[4];
#pragma unroll
  for (int mt = 0; mt < 4; ++mt)
    acc2[mt] = *(const f32x4*)(bias64 + mt * 16 + 4 * g);
#pragma unroll 1
  for (int ks = 0; ks < 4; ++ks) {
    f32x4 aN[2], aC[2];
#pragma unroll
    for (int h = 0; h < 2; ++h) {
      const int mt = 2 * ks + h;
      f32x4 a = zero4;
#pragma unroll
      for (int k2 = 0; k2 < 2; ++k2) {
        bf16x8 aH = frag(0,    64, mt * 16 + lr, k2 * 4 + g, 7);
        bf16x8 aL = frag(8192, 64, mt * 16 + lr, k2 * 4 + g, 7);
        a = MFMA(aH, bxh[k2], a);
        a = MFMA(aH, bxl[k2], a);
        a = MFMA(aL, bxh[k2], a);
      }
      aN[h] = a;
      bf16x8 c8 = frag(16384, 32, mt * 16 + lr, g, 3);
      f32x4 c = MFMA(c8, bxh[1], zero4);
      c = MFMA(c8, bxl[1], c);
      aC[h] = c;
    }
    bf16x8 nh, nl, ch, cl;
#pragma unroll
    for (int u = 0; u < 8; ++u) {
      float vN = fmaxf(aN[u >> 2][u & 3], 0.f);
      bf16 hN = (bf16)vN;
      nh[u] = hN;
      nl[u] = (bf16)(vN - (float)hN);
      float vC = fmaxf(aC[u >> 2][u & 3], 0.f);
      bf16 hC = (bf16)vC;
      ch[u] = hC;
      cl[u] = (bf16)(vC - (float)hC);
    }
#pragma unroll
    for (int mt = 0; mt < 4; ++mt) {
      bf16x8 aH = frag(20480, 128, mt * 16 + lr, ks * 4 + g, 7);
      bf16x8 aL = frag(28672, 128, mt * 16 + lr, ks * 4 + g, 7);
      acc2[mt] = MFMA(aH, nh, acc2[mt]);
      acc2[mt] = MFMA(aH, nl, acc2[mt]);
      acc2[mt] = MFMA(aL, nh, acc2[mt]);
    }
    bf16x8 aCc = frag(36864, 128, lr, ks * 4 + g, 7);
    acc2[3] = MFMA(aCc, ch, acc2[3]);
    acc2[3] = MFMA(aCc, cl, acc2[3]);
  }

  // split (no relu) -> F input frags; acc2 dies here
  bf16x8 b2fh[2], b2fl[2];
#pragma unroll
  for (int s = 0; s < 2; ++s) {
#pragma unroll
    for (int u = 0; u < 8; ++u) {
      float v = acc2[2 * s + (u >> 2)][u & 3];
      bf16 h = (bf16)v;
      b2fh[s][u] = h;
      b2fl[s][u] = (bf16)(v - (float)h);
    }
  }

  // ---- F: layer1 tiles lazy, consumed by F-layer2 slice ks ----
  f32x4 accO[4];
#pragma unroll
  for (int mt = 0; mt < 4; ++mt)
    accO[mt] = *(const f32x4*)(Fb2pad + mt * 16 + 4 * g);
#pragma unroll 1
  for (int ks = 0; ks < 4; ++ks) {
    f32x4 aF[2];
#pragma unroll
    for (int h = 0; h < 2; ++h) {
      const int mt = 2 * ks + h;
      f32x4 a = zero4;
#pragma unroll
      for (int k2 = 0; k2 < 2; ++k2) {
        bf16x8 aH = frag(38912, 64, mt * 16 + lr, k2 * 4 + g, 7);
        bf16x8 aL = frag(47104, 64, mt * 16 + lr, k2 * 4 + g, 7);
        a = MFMA(aH, b2fh[k2], a);
        a = MFMA(aH, b2fl[k2], a);
        a = MFMA(aL, b2fh[k2], a);
      }
      aF[h] = a;
    }
    bf16x8 bh, bl;
#pragma unroll
    for (int u = 0; u < 8; ++u) {
      float v = fmaxf(aF[u >> 2][u & 3], 0.f);
      bf16 h = (bf16)v;
      bh[u] = h;
      bl[u] = (bf16)(v - (float)h);
    }
#pragma unroll
    for (int mt = 0; mt < 4; ++mt) {
      bf16x8 aH = frag(55296, 128, mt * 16 + lr, ks * 4 + g, 7);
      bf16x8 aL = frag(63488, 128, mt * 16 + lr, ks * 4 + g, 7);
      accO[mt] = MFMA(aH, bh, accO[mt]);
      accO[mt] = MFMA(aH, bl, accO[mt]);
      accO[mt] = MFMA(aL, bh, accO[mt]);
    }
  }
  if (g == 2) accO[3][1] = 1.0f;  // f slot 57 = 1.0 (heads bias trick)

  // store f row (bf16, natural slot order)
#pragma unroll
  for (int mt = 0; mt < 4; ++mt) {
    uint32_t w0 = cvt_pk_bf16(accO[mt][0], accO[mt][1]);
    uint32_t w1 = cvt_pk_bf16(accO[mt][2], accO[mt][3]);
    *(uint2*)(fbf + (size_t)row * 64 + mt * 16 + 4 * g) = make_uint2(w0, w1);
  }
}

// ---------------------------------------------------------------------------
// heads: wave = one branch, ALL weights in VGPRs (round-5 proven residency:
// launch_bounds(64,3), VGPR ~96 < 168 cap, FETCH stays ~36MB), stream 1024
// rows/wave. Grid = 54 x 64 chunks = 3456. Round-6 VALU diet retained:
// cvt_pk pack, base-2 logits (W2/Ob2 pre-scaled), raw v_exp_f32,
// incremental pointers. No LDS, no barrier.
// ---------------------------------------------------------------------------
template<bool USE_TMP>
__global__ __launch_bounds__(64, 3) void heads_kernel(
    const bf16* __restrict__ fbf, const bf16* __restrict__ O1T,
    const bf16* __restrict__ O2T, const float* __restrict__ Ob2,
    float* __restrict__ tmp, float* __restrict__ out)
{
  const int bid = blockIdx.x;
  const int br = bid % 54;
  const int chunk = bid / 54;
  const int lane = threadIdx.x;
  const int lr = lane & 15;
  const int g = lane >> 4;
  const f32x4 zero4 = {0.f, 0.f, 0.f, 0.f};

  // branch weights -> registers (once)
  const bf16* a1p = O1T + br * 8192 + lr * 64 + g * 8;
  bf16x8 a1[8][2];
#pragma unroll
  for (int mt = 0; mt < 8; ++mt)
#pragma unroll
    for (int ks = 0; ks < 2; ++ks)
      a1[mt][ks] = *(const bf16x8*)(a1p + mt * 1024 + ks * 32);

  const int e_clamp = (lr < 2) ? lr : 2;
  const bf16* w2p = O2T + br * 384 + e_clamp * 128 + g * 8;
  bf16x8 w2[4];
#pragma unroll
  for (int s2 = 0; s2 < 4; ++s2) w2[s2] = *(const bf16x8*)(w2p + s2 * 32);

  const float LOG2E = 1.4426950408889634f;
  const float b0 = Ob2[br * 3 + 0] * LOG2E;
  const float b1 = Ob2[br * 3 + 1] * LOG2E;
  const float b2s = Ob2[br * 3 + 2] * LOG2E;

  const int row0 = chunk * 1024 + lr;
  const bf16* fp = fbf + (size_t)row0 * 64 + g * 8;
  float* tp = tmp + ((size_t)br * 65536 + row0) * 3;
  float* op = out + (size_t)row0 * 162 + br * 3;

  bf16x8 fb0 = *(const bf16x8*)(fp);
  bf16x8 fb1 = *(const bf16x8*)(fp + 32);

#pragma unroll 1
  for (int it = 0; it < 64; ++it) {
    // prefetch next tile's f (last iter reads 1 tile past the chunk --
    // still inside the workspace (O1T follows fbf), value discarded)
    fp += 1024;
    bf16x8 nf0 = *(const bf16x8*)(fp);
    bf16x8 nf1 = *(const bf16x8*)(fp + 32);

    f32x4 l2 = zero4;
#pragma unroll
    for (int s2 = 0; s2 < 4; ++s2) {
      f32x4 aA = MFMA(a1[2 * s2][0], fb0, zero4);
      f32x4 aB = MFMA(a1[2 * s2 + 1][0], fb0, zero4);
      aA = MFMA(a1[2 * s2][1], fb1, aA);
      aB = MFMA(a1[2 * s2 + 1][1], fb1, aB);
      u32x4 bw;
      bw[0] = cvt_pk_bf16(fmaxf(aA[0], 0.f), fmaxf(aA[1], 0.f));
      bw[1] = cvt_pk_bf16(fmaxf(aA[2], 0.f), fmaxf(aA[3], 0.f));
      bw[2] = cvt_pk_bf16(fmaxf(aB[0], 0.f), fmaxf(aB[1], 0.f));
      bw[3] = cvt_pk_bf16(fmaxf(aB[2], 0.f), fmaxf(aB[3], 0.f));
      l2 = MFMA(w2[s2], __builtin_bit_cast(bf16x8, bw), l2);
    }

    float l0 = l2[0] + b0;
    float l1 = l2[1] + b1;
    float lv = l2[2] + b2s;
    float m = fmaxf(fmaxf(l0, l1), lv);
    float p0 = __builtin_amdgcn_exp2f(l0 - m);
    float p1 = __builtin_amdgcn_exp2f(l1 - m);
    float p2 = __builtin_amdgcn_exp2f(lv - m);
    float rs = __builtin_amdgcn_rcpf(p0 + p1 + p2);
    if (g == 0) {
      if (USE_TMP) {
        tp[0] = p0 * rs; tp[1] = p1 * rs; tp[2] = p2 * rs;
      } else {
        op[0] = p0 * rs; op[1] = p1 * rs; op[2] = p2 * rs;
      }
    }
    if (USE_TMP) tp += 48; else op += 16 * 162;
    fb0 = nf0; fb1 = nf1;
  }
}

// ---------------------------------------------------------------------------
// transpose: tmp[54][65536][3] -> out[65536][162], coalesced both sides.
// ---------------------------------------------------------------------------
__global__ __launch_bounds__(256) void transpose_kernel(
    const float* __restrict__ tmp, float* __restrict__ out)
{
  __shared__ float sh[64 * 163];
  const int tid = threadIdx.x;
  const int rowbase = blockIdx.x * 64;
  for (int t = tid; t < 10368; t += 256) {
    int p = t / 192;
    int q = t - p * 192;
    int r = q / 3;
    int e = q - r * 3;
    sh[r * 163 + p * 3 + e] = tmp[((size_t)p * 65536 + rowbase + r) * 3 + e];
  }
  __syncthreads();
  for (int t = tid; t < 10368; t += 256) {
    int r = t / 162;
    int c = t - r * 162;
    out[(size_t)(rowbase + r) * 162 + c] = sh[r * 163 + c];
  }
}

// ---------------------------------------------------------------------------
extern "C" void kernel_launch(void* const* d_in, const int* in_sizes, int n_in,
                              void* d_out, int out_size, void* d_ws, size_t ws_size,
                              hipStream_t stream)
{
  (void)in_sizes; (void)n_in; (void)out_size;
  const float* x   = (const float*)d_in[0];
  const float* Cw1 = (const float*)d_in[1];
  const float* Cb1 = (const float*)d_in[2];
  const float* Cw2 = (const float*)d_in[3];
  const float* Cb2 = (const float*)d_in[4];
  const float* Nw1 = (const float*)d_in[5];
  const float* Nb1 = (const float*)d_in[6];
  const float* Nw2 = (const float*)d_in[7];
  const float* Nb2 = (const float*)d_in[8];
  const float* Fw1 = (const float*)d_in[9];
  const float* Fb1 = (const float*)d_in[10];
  const float* Fw2 = (const float*)d_in[11];
  const float* Fb2 = (const float*)d_in[12];
  const float* Ow1 = (const float*)d_in[13];
  const float* Ob1 = (const float*)d_in[14];
  const float* Ow2 = (const float*)d_in[15];
  const float* Ob2 = (const float*)d_in[16];

  char* ws = (char*)d_ws;
  bf16*  fbf    = (bf16*)(ws + 0);
  bf16*  O1T    = (bf16*)(ws + 8388608);
  bf16*  O2T    = (bf16*)(ws + 9273344);
  bf16*  blobG  = (bf16*)(ws + 9314816);
  float* bias64 = (float*)(ws + 9458176);
  float* Fb2pad = (float*)(ws + 9458432);
  bf16*  xhi    = (bf16*)(ws + 9458688);
  bf16*  xlo    = (bf16*)(ws + 17847296);
  float* tmp    = (float*)(ws + 26235904);
  const size_t need = 26235904ull + 42467328ull;
  const bool useTmp = ws_size >= need;

  prep_kernel<<<4138, 256, 0, stream>>>(x, Cw1, Cb1, Cw2, Cb2, Nw1, Nb1, Nw2, Nb2,
                                        Fw1, Fb1, Fw2, Fb2, Ow1, Ob1, Ow2,
                                        O1T, O2T, blobG, bias64, Fb2pad, xhi, xlo);
  mlp_kernel<<<256, 1024, 0, stream>>>(xhi, xlo, blobG, bias64, Fb2pad, fbf);
  if (useTmp) {
    heads_kernel<true><<<3456, 64, 0, stream>>>(fbf, O1T, O2T, Ob2, tmp, (float*)d_out);
    transpose_kernel<<<1024, 256, 0, stream>>>(tmp, (float*)d_out);
  } else {
    heads_kernel<false><<<3456, 64, 0, stream>>>(fbf, O1T, O2T, Ob2, tmp, (float*)d_out);
  }
}

// Round 8
// 228.689 us; speedup vs baseline: 1.8777x; 1.0225x over previous
//
#include <hip/hip_runtime.h>
#include <hip/hip_bf16.h>
#include <stdint.h>

typedef __bf16 bf16;
typedef bf16 bf16x8 __attribute__((ext_vector_type(8)));
typedef float f32x4 __attribute__((ext_vector_type(4)));
typedef uint32_t u32x4 __attribute__((ext_vector_type(4)));

#define MFMA(a, b, c) __builtin_amdgcn_mfma_f32_16x16x32_bf16((a), (b), (c), 0, 0, 0)

__device__ __forceinline__ uint32_t cvt_pk_bf16(float lo, float hi) {
  uint32_t r;
  asm("v_cvt_pk_bf16_f32 %0, %1, %2" : "=v"(r) : "v"(lo), "v"(hi));
  return r;
}

// m(k): physical D-row delivered at B k-slot k by the standard b2-pack
// (verified rounds 1-7: inverse of O1T's sigma).
__device__ __forceinline__ int mk(int k) {
  return 32*(k>>5) + 16*((k>>2)&1) + 4*((k>>3)&3) + (k&3);
}

// ---------------------------------------------------------------------------
// Workspace layout (bytes):
//   fbf    @ 0        : [65536][64] bf16 (f padded, slot57=1.0)    8,388,608
//   O1T    @ 8388608  : [54][128][64] bf16 (perm rows, bias@k57)     884,736
//   O2T    @ 9273344  : [54][3][128] bf16  (pre-scaled by log2e)      41,472
//   blobG  @ 9314816  : mlp LDS blob, 71680 bf16 pre-swizzled        143,360
//   bias64 @ 9458176  : [64] f32  (Nb2|Cb2|1|0)                          256
//   Fb2pad @ 9458432  : [64] f32                                         256
//   xhi    @ 9458688  : [65536][64] bf16 (x pre-permuted, hi)       8,388,608
//   xlo    @ 17847296 : [65536][64] bf16 (lo residual)              8,388,608
//   tmp    @ 26235904 : [54][65536][3] f32 (optional)              42,467,328
// ---------------------------------------------------------------------------

__global__ __launch_bounds__(256) void prep_kernel(
    const float* __restrict__ x,
    const float* __restrict__ Cw1, const float* __restrict__ Cb1,
    const float* __restrict__ Cw2, const float* __restrict__ Cb2,
    const float* __restrict__ Nw1, const float* __restrict__ Nb1,
    const float* __restrict__ Nw2, const float* __restrict__ Nb2,
    const float* __restrict__ Fw1, const float* __restrict__ Fb1,
    const float* __restrict__ Fw2, const float* __restrict__ Fb2,
    const float* __restrict__ Ow1, const float* __restrict__ Ob1,
    const float* __restrict__ Ow2,
    bf16* __restrict__ O1T, bf16* __restrict__ O2T,
    bf16* __restrict__ blobG, float* __restrict__ bias64,
    float* __restrict__ Fb2pad, bf16* __restrict__ xhi, bf16* __restrict__ xlo)
{
  const float LOG2E = 1.4426950408889634f;
  int gid = blockIdx.x * 256 + threadIdx.x;
  // O1T[br][m][k] = Ow1[br][k][sigma(m)] (k<57), Ob1[br][sigma(m)] (k==57), 0 else
  if (gid < 442368) {
    int m  = gid & 127;
    int k  = (gid >> 7) & 63;
    int br = gid >> 13;
    int c  = ((m >> 5) << 5) | (((m >> 2) & 3) << 3) | (((m >> 4) & 1) << 2) | (m & 3);
    float v = 0.f;
    if (k < 57)       v = Ow1[(br * 57 + k) * 128 + c];
    else if (k == 57) v = Ob1[br * 128 + c];
    O1T[(br * 128 + m) * 64 + k] = (bf16)v;
    return;
  }
  gid -= 442368;
  // O2T[br][e][c] = Ow2[br][c][e] * log2e  (softmax done in base-2 domain)
  if (gid < 20736) {
    int br  = gid / 384;
    int rem = gid - br * 384;
    int e   = rem >> 7;
    int cc  = rem & 127;
    O2T[gid] = (bf16)(Ow2[(br * 128 + cc) * 3 + e] * LOG2E);
    return;
  }
  gid -= 20736;
  if (gid < 71680) {
    int idx = gid;
    float w = 0.f;
    bool lo = false;
    if (idx < 16384) {                       // A1N hi/lo [128 j][64 k]
      lo = idx >= 8192; int l = idx & 8191;
      int j = l >> 6, cp = l & 63;
      int k = (((cp >> 3) ^ (j & 7)) << 3) | (cp & 7);
      if (k < 54) w = Nw1[k * 128 + j];
      else if (k == 54) w = Nb1[j];
    } else if (idx < 20480) {                // A1C hi [128 j][32 kl] (slots 32+kl)
      int l = idx - 16384;
      int j = l >> 5, cp = l & 31;
      int kl = (((cp >> 3) ^ (j & 3)) << 3) | (cp & 7);
      int s = 32 + kl;
      if (s == 54) w = Cb1[j];
      else if (s >= 56 && s <= 59) w = Cw1[(s - 56) * 128 + j];
    } else if (idx < 36864) {                // A2N hi/lo [64 o][128 k]
      int l = idx - 20480; lo = l >= 8192; l &= 8191;
      int o = l >> 7, cp = l & 127;
      int k = (((cp >> 3) ^ (o & 7)) << 3) | (cp & 7);
      int p = mk(k);
      if (o < 54) w = Nw2[p * 54 + o];
    } else if (idx < 38912) {                // A2C16 hi [16 o'][128 k] (rows 48+o')
      int l = idx - 36864;
      int o = l >> 7, cp = l & 127;
      int k = (((cp >> 3) ^ (o & 7)) << 3) | (cp & 7);
      int p = mk(k);
      if (o >= 6 && o <= 8) w = Cw2[p * 3 + (o - 6)];
    } else if (idx < 55296) {                // A1F hi/lo [128 j][64 k]
      int l = idx - 38912; lo = l >= 8192; l &= 8191;
      int j = l >> 6, cp = l & 63;
      int k = (((cp >> 3) ^ (j & 7)) << 3) | (cp & 7);
      int p = mk(k);
      if (p < 54) w = Fw1[(3 + p) * 128 + j];
      else if (p < 57) w = Fw1[(p - 54) * 128 + j];
      else if (p == 57) w = Fb1[j];
    } else {                                 // A2F hi/lo [64 o][128 k]
      int l = idx - 55296; lo = l >= 8192; l &= 8191;
      int o = l >> 7, cp = l & 127;
      int k = (((cp >> 3) ^ (o & 7)) << 3) | (cp & 7);
      int p = mk(k);
      if (o < 57) w = Fw2[p * 57 + o];
    }
    bf16 h = (bf16)w;
    blobG[gid] = lo ? (bf16)(w - (float)h) : h;
    return;
  }
  gid -= 71680;
  if (gid < 64) {
    float v = 0.f;
    if (gid < 54) v = Nb2[gid];
    else if (gid < 57) v = Cb2[gid - 54];
    else if (gid == 57) v = 1.0f;            // constant-1 row -> F bias slot
    bias64[gid] = v;
    return;
  }
  gid -= 64;
  if (gid < 64) { Fb2pad[gid] = (gid < 57) ? Fb2[gid] : 0.f; return; }
  gid -= 64;
  // x pre-permute + hi/lo split: slots 0-53 = x[4+s], 54 = 1.0, 56-59 = x[0..3]
  if (gid < 524288) {
    int row = gid >> 3;
    int s0 = (gid & 7) * 8;
    const float* xr = x + (size_t)row * 58;
    bf16x8 h8, l8;
#pragma unroll
    for (int u = 0; u < 8; ++u) {
      int s = s0 + u;
      float v;
      if (s < 54) v = xr[4 + s];
      else if (s == 54) v = 1.0f;
      else if (s >= 56 && s <= 59) v = xr[s - 56];
      else v = 0.0f;
      bf16 h = (bf16)v;
      h8[u] = h;
      l8[u] = (bf16)(v - (float)h);
    }
    *(bf16x8*)(xhi + (size_t)row * 64 + s0) = h8;
    *(bf16x8*)(xlo + (size_t)row * 64 + s0) = l8;
  }
}

// ---------------------------------------------------------------------------
// mlp kernel: C/N/F via bf16 hi/lo 3-pass MFMA (fp32-grade accuracy).
// Block = 1024 thr = 16 waves; grid = 256 (1 block/CU); ONE 16-row tile per
// wave. x-fragment loads hoisted ABOVE the LDS staging loop (HBM latency
// hides under staging). ks loops unroll-1 to bound ds_read hoisting.
// ---------------------------------------------------------------------------
__global__ __launch_bounds__(1024)
void mlp_kernel(
    const bf16* __restrict__ xhi, const bf16* __restrict__ xlo,
    const bf16* __restrict__ blobG,
    const float* __restrict__ bias64, const float* __restrict__ Fb2pad,
    bf16* __restrict__ fbf)
{
  __shared__ bf16 blob[71680];
  const int tid = threadIdx.x;
  const int wave = tid >> 6;
  const int lane = tid & 63;
  const int lr = lane & 15;
  const int g = lane >> 4;
  const int row = blockIdx.x * 256 + wave * 16 + lr;

  // issue x-fragment loads first; they complete under the staging loop
  bf16x8 bxh[2], bxl[2];
  bxh[0] = *(const bf16x8*)(xhi + (size_t)row * 64 + g * 8);
  bxh[1] = *(const bf16x8*)(xhi + (size_t)row * 64 + 32 + g * 8);
  bxl[0] = *(const bf16x8*)(xlo + (size_t)row * 64 + g * 8);
  bxl[1] = *(const bf16x8*)(xlo + (size_t)row * 64 + 32 + g * 8);

  {
    const uint4* src = (const uint4*)blobG;
    uint4* dst = (uint4*)blob;
    for (int t = tid; t < 8960; t += 1024) dst[t] = src[t];
  }
  __syncthreads();

  const f32x4 zero4 = {0.f, 0.f, 0.f, 0.f};

  auto frag = [&](int base, int stride, int row_, int chunk, int mask) -> bf16x8 {
    int c = chunk ^ (row_ & mask);
    return *(const bf16x8*)(blob + base + row_ * stride + c * 8);
  };

  // ---- N/C: layer1 tiles produced lazily, consumed by layer2 slice ks ----
  f32x4 acc2[4];
#pragma unroll
  for (int mt = 0; mt < 4; ++mt)
    acc2[mt] = *(const f32x4*)(bias64 + mt * 16 + 4 * g);
#pragma unroll 1
  for (int ks = 0; ks < 4; ++ks) {
    f32x4 aN[2], aC[2];
#pragma unroll
    for (int h = 0; h < 2; ++h) {
      const int mt = 2 * ks + h;
      f32x4 a = zero4;
#pragma unroll
      for (int k2 = 0; k2 < 2; ++k2) {
        bf16x8 aH = frag(0,    64, mt * 16 + lr, k2 * 4 + g, 7);
        bf16x8 aL = frag(8192, 64, mt * 16 + lr, k2 * 4 + g, 7);
        a = MFMA(aH, bxh[k2], a);
        a = MFMA(aH, bxl[k2], a);
        a = MFMA(aL, bxh[k2], a);
      }
      aN[h] = a;
      bf16x8 c8 = frag(16384, 32, mt * 16 + lr, g, 3);
      f32x4 c = MFMA(c8, bxh[1], zero4);
      c = MFMA(c8, bxl[1], c);
      aC[h] = c;
    }
    bf16x8 nh, nl, ch, cl;
#pragma unroll
    for (int u = 0; u < 8; ++u) {
      float vN = fmaxf(aN[u >> 2][u & 3], 0.f);
      bf16 hN = (bf16)vN;
      nh[u] = hN;
      nl[u] = (bf16)(vN - (float)hN);
      float vC = fmaxf(aC[u >> 2][u & 3], 0.f);
      bf16 hC = (bf16)vC;
      ch[u] = hC;
      cl[u] = (bf16)(vC - (float)hC);
    }
#pragma unroll
    for (int mt = 0; mt < 4; ++mt) {
      bf16x8 aH = frag(20480, 128, mt * 16 + lr, ks * 4 + g, 7);
      bf16x8 aL = frag(28672, 128, mt * 16 + lr, ks * 4 + g, 7);
      acc2[mt] = MFMA(aH, nh, acc2[mt]);
      acc2[mt] = MFMA(aH, nl, acc2[mt]);
      acc2[mt] = MFMA(aL, nh, acc2[mt]);
    }
    bf16x8 aCc = frag(36864, 128, lr, ks * 4 + g, 7);
    acc2[3] = MFMA(aCc, ch, acc2[3]);
    acc2[3] = MFMA(aCc, cl, acc2[3]);
  }

  // split (no relu) -> F input frags; acc2 dies here
  bf16x8 b2fh[2], b2fl[2];
#pragma unroll
  for (int s = 0; s < 2; ++s) {
#pragma unroll
    for (int u = 0; u < 8; ++u) {
      float v = acc2[2 * s + (u >> 2)][u & 3];
      bf16 h = (bf16)v;
      b2fh[s][u] = h;
      b2fl[s][u] = (bf16)(v - (float)h);
    }
  }

  // ---- F: layer1 tiles lazy, consumed by F-layer2 slice ks ----
  f32x4 accO[4];
#pragma unroll
  for (int mt = 0; mt < 4; ++mt)
    accO[mt] = *(const f32x4*)(Fb2pad + mt * 16 + 4 * g);
#pragma unroll 1
  for (int ks = 0; ks < 4; ++ks) {
    f32x4 aF[2];
#pragma unroll
    for (int h = 0; h < 2; ++h) {
      const int mt = 2 * ks + h;
      f32x4 a = zero4;
#pragma unroll
      for (int k2 = 0; k2 < 2; ++k2) {
        bf16x8 aH = frag(38912, 64, mt * 16 + lr, k2 * 4 + g, 7);
        bf16x8 aL = frag(47104, 64, mt * 16 + lr, k2 * 4 + g, 7);
        a = MFMA(aH, b2fh[k2], a);
        a = MFMA(aH, b2fl[k2], a);
        a = MFMA(aL, b2fh[k2], a);
      }
      aF[h] = a;
    }
    bf16x8 bh, bl;
#pragma unroll
    for (int u = 0; u < 8; ++u) {
      float v = fmaxf(aF[u >> 2][u & 3], 0.f);
      bf16 h = (bf16)v;
      bh[u] = h;
      bl[u] = (bf16)(v - (float)h);
    }
#pragma unroll
    for (int mt = 0; mt < 4; ++mt) {
      bf16x8 aH = frag(55296, 128, mt * 16 + lr, ks * 4 + g, 7);
      bf16x8 aL = frag(63488, 128, mt * 16 + lr, ks * 4 + g, 7);
      accO[mt] = MFMA(aH, bh, accO[mt]);
      accO[mt] = MFMA(aH, bl, accO[mt]);
      accO[mt] = MFMA(aL, bh, accO[mt]);
    }
  }
  if (g == 2) accO[3][1] = 1.0f;  // f slot 57 = 1.0 (heads bias trick)

  // store f row (bf16, natural slot order)
#pragma unroll
  for (int mt = 0; mt < 4; ++mt) {
    uint32_t w0 = cvt_pk_bf16(accO[mt][0], accO[mt][1]);
    uint32_t w1 = cvt_pk_bf16(accO[mt][2], accO[mt][3]);
    *(uint2*)(fbf + (size_t)row * 64 + mt * 16 + 4 * g) = make_uint2(w0, w1);
  }
}

// ---------------------------------------------------------------------------
// heads: wave = one branch, ALL weights in VGPRs (r7: VGPR=60, FETCH 36MB
// proves residency at launch_bounds(64,3)). Grid = 54 x 128 chunks = 6912
// waves = 6.75/SIMD potential (r7's 3456 was grid-limited at 26.7% occ).
// VALU diet: cvt_pk pack, base-2 logits, raw v_exp_f32, incr. pointers.
// ---------------------------------------------------------------------------
template<bool USE_TMP>
__global__ __launch_bounds__(64, 3) void heads_kernel(
    const bf16* __restrict__ fbf, const bf16* __restrict__ O1T,
    const bf16* __restrict__ O2T, const float* __restrict__ Ob2,
    float* __restrict__ tmp, float* __restrict__ out)
{
  const int bid = blockIdx.x;
  const int br = bid % 54;
  const int chunk = bid / 54;
  const int lane = threadIdx.x;
  const int lr = lane & 15;
  const int g = lane >> 4;
  const f32x4 zero4 = {0.f, 0.f, 0.f, 0.f};

  // branch weights -> registers (once)
  const bf16* a1p = O1T + br * 8192 + lr * 64 + g * 8;
  bf16x8 a1[8][2];
#pragma unroll
  for (int mt = 0; mt < 8; ++mt)
#pragma unroll
    for (int ks = 0; ks < 2; ++ks)
      a1[mt][ks] = *(const bf16x8*)(a1p + mt * 1024 + ks * 32);

  const int e_clamp = (lr < 2) ? lr : 2;
  const bf16* w2p = O2T + br * 384 + e_clamp * 128 + g * 8;
  bf16x8 w2[4];
#pragma unroll
  for (int s2 = 0; s2 < 4; ++s2) w2[s2] = *(const bf16x8*)(w2p + s2 * 32);

  const float LOG2E = 1.4426950408889634f;
  const float b0 = Ob2[br * 3 + 0] * LOG2E;
  const float b1 = Ob2[br * 3 + 1] * LOG2E;
  const float b2s = Ob2[br * 3 + 2] * LOG2E;

  const int row0 = chunk * 512 + lr;
  const bf16* fp = fbf + (size_t)row0 * 64 + g * 8;
  float* tp = tmp + ((size_t)br * 65536 + row0) * 3;
  float* op = out + (size_t)row0 * 162 + br * 3;

  bf16x8 fb0 = *(const bf16x8*)(fp);
  bf16x8 fb1 = *(const bf16x8*)(fp + 32);

#pragma unroll 1
  for (int it = 0; it < 32; ++it) {
    // prefetch next tile's f (last iter reads 1 tile past the chunk --
    // still inside the workspace, value discarded)
    fp += 1024;
    bf16x8 nf0 = *(const bf16x8*)(fp);
    bf16x8 nf1 = *(const bf16x8*)(fp + 32);

    f32x4 l2 = zero4;
#pragma unroll
    for (int s2 = 0; s2 < 4; ++s2) {
      f32x4 aA = MFMA(a1[2 * s2][0], fb0, zero4);
      f32x4 aB = MFMA(a1[2 * s2 + 1][0], fb0, zero4);
      aA = MFMA(a1[2 * s2][1], fb1, aA);
      aB = MFMA(a1[2 * s2 + 1][1], fb1, aB);
      u32x4 bw;
      bw[0] = cvt_pk_bf16(fmaxf(aA[0], 0.f), fmaxf(aA[1], 0.f));
      bw[1] = cvt_pk_bf16(fmaxf(aA[2], 0.f), fmaxf(aA[3], 0.f));
      bw[2] = cvt_pk_bf16(fmaxf(aB[0], 0.f), fmaxf(aB[1], 0.f));
      bw[3] = cvt_pk_bf16(fmaxf(aB[2], 0.f), fmaxf(aB[3], 0.f));
      l2 = MFMA(w2[s2], __builtin_bit_cast(bf16x8, bw), l2);
    }

    float l0 = l2[0] + b0;
    float l1 = l2[1] + b1;
    float lv = l2[2] + b2s;
    float m = fmaxf(fmaxf(l0, l1), lv);
    float p0 = __builtin_amdgcn_exp2f(l0 - m);
    float p1 = __builtin_amdgcn_exp2f(l1 - m);
    float p2 = __builtin_amdgcn_exp2f(lv - m);
    float rs = __builtin_amdgcn_rcpf(p0 + p1 + p2);
    if (g == 0) {
      if (USE_TMP) {
        tp[0] = p0 * rs; tp[1] = p1 * rs; tp[2] = p2 * rs;
      } else {
        op[0] = p0 * rs; op[1] = p1 * rs; op[2] = p2 * rs;
      }
    }
    if (USE_TMP) tp += 48; else op += 16 * 162;
    fb0 = nf0; fb1 = nf1;
  }
}

// ---------------------------------------------------------------------------
// transpose: tmp[54][65536][3] -> out[65536][162], coalesced both sides.
// ---------------------------------------------------------------------------
__global__ __launch_bounds__(256) void transpose_kernel(
    const float* __restrict__ tmp, float* __restrict__ out)
{
  __shared__ float sh[64 * 163];
  const int tid = threadIdx.x;
  const int rowbase = blockIdx.x * 64;
  for (int t = tid; t < 10368; t += 256) {
    int p = t / 192;
    int q = t - p * 192;
    int r = q / 3;
    int e = q - r * 3;
    sh[r * 163 + p * 3 + e] = tmp[((size_t)p * 65536 + rowbase + r) * 3 + e];
  }
  __syncthreads();
  for (int t = tid; t < 10368; t += 256) {
    int r = t / 162;
    int c = t - r * 162;
    out[(size_t)(rowbase + r) * 162 + c] = sh[r * 163 + c];
  }
}

// ---------------------------------------------------------------------------
extern "C" void kernel_launch(void* const* d_in, const int* in_sizes, int n_in,
                              void* d_out, int out_size, void* d_ws, size_t ws_size,
                              hipStream_t stream)
{
  (void)in_sizes; (void)n_in; (void)out_size;
  const float* x   = (const float*)d_in[0];
  const float* Cw1 = (const float*)d_in[1];
  const float* Cb1 = (const float*)d_in[2];
  const float* Cw2 = (const float*)d_in[3];
  const float* Cb2 = (const float*)d_in[4];
  const float* Nw1 = (const float*)d_in[5];
  const float* Nb1 = (const float*)d_in[6];
  const float* Nw2 = (const float*)d_in[7];
  const float* Nb2 = (const float*)d_in[8];
  const float* Fw1 = (const float*)d_in[9];
  const float* Fb1 = (const float*)d_in[10];
  const float* Fw2 = (const float*)d_in[11];
  const float* Fb2 = (const float*)d_in[12];
  const float* Ow1 = (const float*)d_in[13];
  const float* Ob1 = (const float*)d_in[14];
  const float* Ow2 = (const float*)d_in[15];
  const float* Ob2 = (const float*)d_in[16];

  char* ws = (char*)d_ws;
  bf16*  fbf    = (bf16*)(ws + 0);
  bf16*  O1T    = (bf16*)(ws + 8388608);
  bf16*  O2T    = (bf16*)(ws + 9273344);
  bf16*  blobG  = (bf16*)(ws + 9314816);
  float* bias64 = (float*)(ws + 9458176);
  float* Fb2pad = (float*)(ws + 9458432);
  bf16*  xhi    = (bf16*)(ws + 9458688);
  bf16*  xlo    = (bf16*)(ws + 17847296);
  float* tmp    = (float*)(ws + 26235904);
  const size_t need = 26235904ull + 42467328ull;
  const bool useTmp = ws_size >= need;

  prep_kernel<<<4138, 256, 0, stream>>>(x, Cw1, Cb1, Cw2, Cb2, Nw1, Nb1, Nw2, Nb2,
                                        Fw1, Fb1, Fw2, Fb2, Ow1, Ob1, Ow2,
                                        O1T, O2T, blobG, bias64, Fb2pad, xhi, xlo);
  mlp_kernel<<<256, 1024, 0, stream>>>(xhi, xlo, blobG, bias64, Fb2pad, fbf);
  if (useTmp) {
    heads_kernel<true><<<6912, 64, 0, stream>>>(fbf, O1T, O2T, Ob2, tmp, (float*)d_out);
    transpose_kernel<<<1024, 256, 0, stream>>>(tmp, (float*)d_out);
  } else {
    heads_kernel<false><<<6912, 64, 0, stream>>>(fbf, O1T, O2T, Ob2, tmp, (float*)d_out);
  }
}